// Round 7
// baseline (440.897 us; speedup 1.0000x reference)
//
#include <hip/hip_runtime.h>
#include <hip/hip_fp16.h>

#define N_NODES 50000
#define N_EDGES 800000
#define D_FEAT 64
#define K_HOPS 8
#define OUT_STRIDE ((K_HOPS + 1) * D_FEAT)  // 576
#define NPART 128                 // edge-chunk partitions (1 block/CU @ 100KB LDS)
#define CHUNK (N_EDGES / NPART)   // 6250
#define NWORD (N_NODES / 2)       // 2 nodes per u32 histogram word

#define SCAN_WORDS 512            // words per scan block = 1024 nodes
#define SCAN_NB ((NWORD + SCAN_WORDS - 1) / SCAN_WORDS)  // 49

// ---------------- ws layout (bytes) ----------------
// No global atomics in CSR build; every buffer fully overwritten -> no big memset.
// P word layout per node-pair w (nodes 2w, 2w+1): byte0=src(2w), byte1=src(2w+1),
// byte2=dst(2w), byte3=dst(2w+1). Per-chunk per-node counts << 255 (Poisson(0.125)).
#define ALIGN256(x) (((x) + 255) & ~(size_t)255)
static const size_t OFF_P     = 0;                                           // u32[128][25000]
static const size_t OFF_BASES = OFF_P + (size_t)NPART * NWORD * 4;           // int[128][N]
static const size_t OFF_OFF   = ALIGN256(OFF_BASES + (size_t)NPART * N_NODES * 4); // int[N+1]
static const size_t OFF_BSUM  = ALIGN256(OFF_OFF   + (size_t)(N_NODES + 1) * 4);   // int[64]
static const size_t OFF_TOTW  = ALIGN256(OFF_BSUM  + 64 * 4);                // u32[NWORD]
static const size_t OFF_DINV  = ALIGN256(OFF_TOTW  + (size_t)NWORD * 4);     // float[N]
static const size_t OFF_DCNT  = ALIGN256(OFF_DINV  + (size_t)N_NODES * 4);   // int[256] (memset)
static const size_t OFF_DWORK = ALIGN256(OFF_DCNT  + 256 * 4);               // int[256]
static const size_t OFF_PERM  = ALIGN256(OFF_DWORK + 256 * 4);               // int[N]
static const size_t OFF_CSR   = ALIGN256(OFF_PERM  + (size_t)N_NODES * 4);   // int[E]
static const size_t OFF_XA    = ALIGN256(OFF_CSR   + (size_t)N_EDGES * 4);   // half[(N+1)*64]
static const size_t OFF_XB    = ALIGN256(OFF_XA + (size_t)(N_NODES + 1) * D_FEAT * 2);

__device__ __forceinline__ unsigned pack_h2(float a, float b) {
    union { __half2 h; unsigned u; } c;
    c.h = __floats2half2_rn(a, b);
    return c.u;
}
__device__ __forceinline__ float2 unpack_h2(unsigned u) {
    union { unsigned u; __half2 h; } c;
    c.u = u;
    return __half22float2(c.h);
}

// ---------------- preprocessing: zero-global-atomic counting sort ----------------

// ONE pass: per-chunk LDS histogram of src AND dst packed 4xu8 per word.
// (r6 post-mortem: two-pass hist + split reductions made preprocessing ~105us,
// no cheaper than r2's global atomics. This halves sweeps, edge reads, dumps.)
__global__ __launch_bounds__(256, 1) void k_hist(const int* __restrict__ src,
                                                 const int* __restrict__ dst,
                                                 unsigned* __restrict__ p) {
    __shared__ unsigned h[NWORD];  // 100,000 B
    int t = threadIdx.x;
    int base = blockIdx.x * CHUNK;
    for (int w = t; w < NWORD; w += 256) h[w] = 0u;
    __syncthreads();
    for (int j = t; j < CHUNK; j += 256) {
        int s = src[base + j], d = dst[base + j];
        if (s != d) {
            atomicAdd(&h[s >> 1], 1u << (8 * (s & 1)));        // src: bytes 0/1
            atomicAdd(&h[d >> 1], 65536u << (8 * (d & 1)));    // dst: bytes 2/3
        }
    }
    __syncthreads();
    unsigned* o = p + (size_t)blockIdx.x * NWORD;
    for (int w = t; w < NWORD; w += 256) o[w] = h[w];
}

// One coalesced reduction of the packed partials -> dinv (from src bytes)
// AND totW (dst totals, u16-packed). Byte-lane sums stay < 256 (deg <= ~60).
__global__ void k_sum(const unsigned* __restrict__ p, float* __restrict__ dinv,
                      unsigned* __restrict__ totW) {
    int w = blockIdx.x * blockDim.x + threadIdx.x;
    if (w >= NWORD) return;
    unsigned s0 = 0, s1 = 0, s2 = 0, s3 = 0;
    #pragma unroll 4
    for (int c = 0; c < NPART; c += 4) {
        s0 += p[(size_t)(c + 0) * NWORD + w];
        s1 += p[(size_t)(c + 1) * NWORD + w];
        s2 += p[(size_t)(c + 2) * NWORD + w];
        s3 += p[(size_t)(c + 3) * NWORD + w];
    }
    unsigned s = (s0 + s1) + (s2 + s3);
    dinv[2 * w + 0] = rsqrtf((float)((s & 0xffu) + 1u));          // +1 self loop
    dinv[2 * w + 1] = rsqrtf((float)(((s >> 8) & 0xffu) + 1u));
    totW[w] = ((s >> 16) & 0xffu) | ((s >> 24) << 16);            // dst degs packed u16
}

// scan stage 1: per-block (1024 nodes) sums of totW (100KB total)
__global__ void k_scan_sums(const unsigned* __restrict__ totW, int* __restrict__ bsum) {
    __shared__ int lds[256];
    int b = blockIdx.x, t = threadIdx.x;
    int wend = min((b + 1) * SCAN_WORDS, NWORD);
    int tot = 0;
    for (int w = b * SCAN_WORDS + t; w < wend; w += 256) {
        unsigned v = totW[w];
        tot += (int)(v & 0xffffu) + (int)(v >> 16);
    }
    lds[t] = tot; __syncthreads();
    for (int str = 128; str > 0; str >>= 1) {
        if (t < str) lds[t] += lds[t + str];
        __syncthreads();
    }
    if (t == 0) bsum[b] = lds[0];
}

// scan stage 2: single-wave exclusive scan of the 49 block sums
__global__ void k_scan_top(int* __restrict__ bsum) {
    int lane = threadIdx.x;  // blockDim = 64
    int orig = (lane < SCAN_NB) ? bsum[lane] : 0;
    int v = orig;
    for (int d = 1; d < 64; d <<= 1) {
        int u = __shfl_up(v, d, 64);
        if (lane >= d) v += u;
    }
    if (lane < SCAN_NB) bsum[lane] = v - orig;  // exclusive
}

// scan stage 3: down-sweep writing off[] only
__global__ void k_scan_downA(const unsigned* __restrict__ totW, const int* __restrict__ bsum,
                             int* __restrict__ off) {
    __shared__ int lds[256];
    int b = blockIdx.x, t = threadIdx.x;
    int w0 = b * SCAN_WORDS + 2 * t;
    unsigned t0 = (w0 < NWORD) ? totW[w0] : 0u;
    unsigned t1 = (w0 + 1 < NWORD) ? totW[w0 + 1] : 0u;
    int n[4] = { (int)(t0 & 0xffffu), (int)(t0 >> 16),
                 (int)(t1 & 0xffffu), (int)(t1 >> 16) };
    int tsum = (n[0] + n[1]) + (n[2] + n[3]);
    lds[t] = tsum; __syncthreads();
    int x = tsum;
    for (int d = 1; d < 256; d <<= 1) {   // Hillis-Steele inclusive scan
        int u = (t >= d) ? lds[t - d] : 0;
        __syncthreads();
        x += u;
        lds[t] = x;
        __syncthreads();
    }
    int pfx = (x - tsum) + bsum[b];
    #pragma unroll
    for (int j = 0; j < 4; ++j) {
        int node = 2 * w0 + j;
        if (node < N_NODES) {
            off[node] = pfx;
            pfx += n[j];
        } else if (node == N_NODES) {
            off[node] = pfx;
        }
    }
}

// bases[c][node] = off[node] + prefix over chunks of per-chunk dst count.
// One LANE per node: reads and writes lane-consecutive -> fully coalesced.
__global__ void k_bases(const unsigned* __restrict__ p, const int* __restrict__ off,
                        int* __restrict__ bases) {
    int node = blockIdx.x * blockDim.x + threadIdx.x;
    if (node >= N_NODES) return;
    int w = node >> 1;
    int sh = 16 + 8 * (node & 1);  // dst byte lane
    int acc = off[node];
    for (int c = 0; c < NPART; ++c) {
        bases[(size_t)c * N_NODES + node] = acc;
        acc += (int)((p[(size_t)c * NWORD + w] >> sh) & 0xffu);
    }
}

// scatter via LDS re-histogram (dst only, u16-packed): the LDS atomicAdd
// return value IS the within-(chunk,dst) slot. No global atomics.
__global__ __launch_bounds__(256, 1) void k_scatter(const int* __restrict__ src,
                                                    const int* __restrict__ dst,
                                                    const int* __restrict__ bases,
                                                    int* __restrict__ csr) {
    __shared__ unsigned h[NWORD];  // 100,000 B
    int t = threadIdx.x;
    int base = blockIdx.x * CHUNK;
    const int* bp = bases + (size_t)blockIdx.x * N_NODES;
    for (int w = t; w < NWORD; w += 256) h[w] = 0u;
    __syncthreads();
    for (int j = t; j < CHUNK; j += 256) {
        int s = src[base + j], d = dst[base + j];
        if (s == d) continue;
        unsigned old = atomicAdd(&h[d >> 1], (d & 1) ? 65536u : 1u);
        unsigned pw = (d & 1) ? (old >> 16) : (old & 0xffffu);
        csr[bp[d] + (int)pw] = s;
    }
}

// ---------------- degree-sorted quad packing ----------------
// Wave loop bound = max degree over its 4 nodes; E[max4 @ Poisson(16)] ~ 22 vs
// mean 16 -> ~27% wasted gather slots. Counting-sort nodes by degree so quad
// members have ~equal degree. bin = deg*4 | (node&3): sub-binning quarters
// atomic contention while preserving degree grouping.
__global__ void k_dcount(const int* __restrict__ off, int* __restrict__ dcnt) {
    int node = blockIdx.x * blockDim.x + threadIdx.x;
    if (node >= N_NODES) return;
    int deg = off[node + 1] - off[node];
    atomicAdd(&dcnt[(min(deg, 63) << 2) | (node & 3)], 1);
}

__global__ void k_dscan(const int* __restrict__ dcnt, int* __restrict__ dwork) {
    __shared__ int lds[256];
    int t = threadIdx.x;  // one block, 256 threads
    int v = dcnt[t];
    lds[t] = v; __syncthreads();
    int x = v;
    for (int d = 1; d < 256; d <<= 1) {
        int u = (t >= d) ? lds[t - d] : 0;
        __syncthreads();
        x += u;
        lds[t] = x;
        __syncthreads();
    }
    dwork[t] = x - v;  // exclusive
}

__global__ void k_dperm(const int* __restrict__ off, int* __restrict__ dwork,
                        int* __restrict__ perm) {
    int node = blockIdx.x * blockDim.x + threadIdx.x;
    if (node >= N_NODES) return;
    int deg = off[node + 1] - off[node];
    int pos = atomicAdd(&dwork[(min(deg, 63) << 2) | (node & 3)], 1);
    perm[pos] = node;
}

// ---------------- compute kernels ----------------

// x0: feature -> out col 0 (fp32) and XB = y0 = dinv * x (fp16 compact).
// Also zeroes row N of XB (the predication zero-row for hop gathers).
__global__ void k_x0(const float4* __restrict__ feat4, float4* __restrict__ out4,
                     uint2* __restrict__ y0, const float* __restrict__ dinv) {
    int t = blockIdx.x * blockDim.x + threadIdx.x;  // over (N+1)*16
    if (t >= (N_NODES + 1) * 16) return;
    int row = t >> 4;
    if (row < N_NODES) {
        float4 v = feat4[t];
        out4[(size_t)row * (OUT_STRIDE / 4) + (t & 15)] = v;
        float di = dinv[row];
        uint2 w;
        w.x = pack_h2(v.x * di, v.y * di);
        w.y = pack_h2(v.z * di, v.w * di);
        y0[t] = w;
    } else {
        y0[t] = make_uint2(0u, 0u);  // zero row
    }
}

// Quad-node hop over degree-sorted perm: 4 similar-degree nodes per wave
// (16 lanes x 8B each -> one gather instruction fetches 4 rows of 128B).
// Weight-free accumulate: t_i = sum y[j] + y[i]; out = dinv*t; y' = dinv^2*t.
template <bool WRITE_HALF>
__global__ __launch_bounds__(256) void k_hop4(
    const uint2* __restrict__ yin,   // (N+1) x 16 x uint2
    float4* __restrict__ outcol4,    // (float4*)out + k*16; row stride 144
    uint2* __restrict__ yout,
    const int* __restrict__ off, const int* __restrict__ csr,
    const float* __restrict__ dinv, const int* __restrict__ perm) {
    int qw = (blockIdx.x * blockDim.x + threadIdx.x) >> 6;  // quad id, < 12500
    int lane = threadIdx.x & 63;
    int f = lane & 15;                     // feature quad: features [4f, 4f+4)
    int node = perm[qw * 4 + (lane >> 4)]; // degree-sorted packing
    int e0 = off[node], e1 = off[node + 1];
    float di = dinv[node];
    uint2 sv = yin[node * 16 + f];
    float2 lo = unpack_h2(sv.x), hi = unpack_h2(sv.y);
    float a0 = lo.x, a1 = lo.y, a2 = hi.x, a3 = hi.y;  // self term

    int nm = e1 - e0;  // wave-wide max degree (quad members ~equal now)
    #pragma unroll
    for (int d = 32; d; d >>= 1) nm = max(nm, __shfl_xor(nm, d, 64));

    auto FETCH = [&](int j) -> int {
        int idx = e0 + j;
        int c = csr[idx < e1 ? idx : 0];  // safe broadcast addr
        return (idx < e1) ? c : N_NODES;  // zero row when exhausted
    };

    int c0 = FETCH(0), c1 = FETCH(1), c2 = FETCH(2), c3 = FETCH(3);
    for (int j = 0; j < nm; j += 4) {
        int d0 = FETCH(j + 4), d1 = FETCH(j + 5), d2 = FETCH(j + 6), d3 = FETCH(j + 7);
        uint2 q0 = yin[c0 * 16 + f];
        uint2 q1 = yin[c1 * 16 + f];
        uint2 q2 = yin[c2 * 16 + f];
        uint2 q3 = yin[c3 * 16 + f];
        float2 t;
        t = unpack_h2(q0.x); a0 += t.x; a1 += t.y;
        t = unpack_h2(q0.y); a2 += t.x; a3 += t.y;
        t = unpack_h2(q1.x); a0 += t.x; a1 += t.y;
        t = unpack_h2(q1.y); a2 += t.x; a3 += t.y;
        t = unpack_h2(q2.x); a0 += t.x; a1 += t.y;
        t = unpack_h2(q2.y); a2 += t.x; a3 += t.y;
        t = unpack_h2(q3.x); a0 += t.x; a1 += t.y;
        t = unpack_h2(q3.y); a2 += t.x; a3 += t.y;
        c0 = d0; c1 = d1; c2 = d2; c3 = d3;
    }

    outcol4[(size_t)node * (OUT_STRIDE / 4) + f] =
        make_float4(di * a0, di * a1, di * a2, di * a3);
    if (WRITE_HALF) {
        float di2 = di * di;
        uint2 w;
        w.x = pack_h2(di2 * a0, di2 * a1);
        w.y = pack_h2(di2 * a2, di2 * a3);
        yout[node * 16 + f] = w;
        if (blockIdx.x == 0 && threadIdx.x < 16)
            yout[N_NODES * 16 + threadIdx.x] = make_uint2(0u, 0u);  // zero row
    }
}

// ---------------- launch ----------------

extern "C" void kernel_launch(void* const* d_in, const int* in_sizes, int n_in,
                              void* d_out, int out_size, void* d_ws, size_t ws_size,
                              hipStream_t stream) {
    const float* feature = (const float*)d_in[0];
    const int* edge = (const int*)d_in[1];
    const int* src = edge;            // edge_index[0]
    const int* dst = edge + N_EDGES;  // edge_index[1]
    float* out = (float*)d_out;
    char* ws = (char*)d_ws;

    unsigned* p     = (unsigned*)(ws + OFF_P);
    int*      bases = (int*)(ws + OFF_BASES);
    int*      off   = (int*)(ws + OFF_OFF);
    int*      bsum  = (int*)(ws + OFF_BSUM);
    unsigned* totW  = (unsigned*)(ws + OFF_TOTW);
    float*    dinv  = (float*)(ws + OFF_DINV);
    int*      dcnt  = (int*)(ws + OFF_DCNT);
    int*      dwork = (int*)(ws + OFF_DWORK);
    int*      perm  = (int*)(ws + OFF_PERM);
    int*      csr   = (int*)(ws + OFF_CSR);
    uint2*    xa    = (uint2*)(ws + OFF_XA);
    uint2*    xb    = (uint2*)(ws + OFF_XB);

    const int TB = 256;
    const int NB_NODES = (N_NODES + TB - 1) / TB;
    // ---- build normalization + CSR: zero global atomics in the sort
    hipMemsetAsync(dcnt, 0, 256 * 4, stream);  // 1KB, for degree binning
    k_hist<<<NPART, 256, 0, stream>>>(src, dst, p);
    k_sum<<<(NWORD + TB - 1) / TB, TB, 0, stream>>>(p, dinv, totW);
    k_x0<<<((N_NODES + 1) * 16 + TB - 1) / TB, TB, 0, stream>>>(
        (const float4*)feature, (float4*)out, xb, dinv);
    k_scan_sums<<<SCAN_NB, 256, 0, stream>>>(totW, bsum);
    k_scan_top<<<1, 64, 0, stream>>>(bsum);
    k_scan_downA<<<SCAN_NB, 256, 0, stream>>>(totW, bsum, off);
    k_bases<<<NB_NODES, TB, 0, stream>>>(p, off, bases);
    k_scatter<<<NPART, 256, 0, stream>>>(src, dst, bases, csr);
    // ---- degree-sorted quad packing
    k_dcount<<<NB_NODES, TB, 0, stream>>>(off, dcnt);
    k_dscan<<<1, 256, 0, stream>>>(dcnt, dwork);
    k_dperm<<<NB_NODES, TB, 0, stream>>>(off, dwork, perm);
    // ---- K hops, fp16 ping-pong y buffers (XB -> XA -> XB -> ...)
    const int hop_blocks = (N_NODES / 4) * 64 / TB;  // 3125
    for (int k = 1; k <= K_HOPS; ++k) {
        const uint2* yin = (k & 1) ? xb : xa;
        uint2* yout      = (k & 1) ? xa : xb;
        float4* outcol4 = (float4*)out + (size_t)k * 16;
        if (k < K_HOPS)
            k_hop4<true><<<hop_blocks, TB, 0, stream>>>(yin, outcol4, yout, off, csr, dinv, perm);
        else
            k_hop4<false><<<hop_blocks, TB, 0, stream>>>(yin, outcol4, nullptr, off, csr, dinv, perm);
    }
}

// Round 8
// 326.830 us; speedup vs baseline: 1.3490x; 1.3490x over previous
//
#include <hip/hip_runtime.h>
#include <hip/hip_fp16.h>

#define N_NODES 50000
#define N_EDGES 800000
#define D_FEAT 64
#define K_HOPS 8
#define OUT_STRIDE ((K_HOPS + 1) * D_FEAT)  // 576
#define NPART 128                 // edge-chunk partitions (1 block/CU @ 100KB LDS)
#define CHUNK (N_EDGES / NPART)   // 6250
#define NWORD (N_NODES / 2)       // 2 nodes per u32 histogram word

#define SCAN_WORDS 512            // words per scan block = 1024 nodes
#define SCAN_NB ((NWORD + SCAN_WORDS - 1) / SCAN_WORDS)  // 49

// ---------------- ws layout (bytes) ----------------
// No global atomics anywhere; every buffer fully overwritten -> no memset.
// P word layout per node-pair w (nodes 2w, 2w+1): byte0=src(2w), byte1=src(2w+1),
// byte2=dst(2w), byte3=dst(2w+1). Per-chunk per-node counts << 255.
#define ALIGN256(x) (((x) + 255) & ~(size_t)255)
static const size_t OFF_P     = 0;                                           // u32[128][25000]
static const size_t OFF_BASES = OFF_P + (size_t)NPART * NWORD * 4;           // int[128][N]
static const size_t OFF_OFF   = ALIGN256(OFF_BASES + (size_t)NPART * N_NODES * 4); // int[N+1]
static const size_t OFF_BSUM  = ALIGN256(OFF_OFF   + (size_t)(N_NODES + 1) * 4);   // int[64]
static const size_t OFF_TOTW  = ALIGN256(OFF_BSUM  + 64 * 4);                // u32[NWORD]
static const size_t OFF_DINV  = ALIGN256(OFF_TOTW  + (size_t)NWORD * 4);     // float[N]
static const size_t OFF_CSR   = ALIGN256(OFF_DINV  + (size_t)N_NODES * 4);   // int[E]
static const size_t OFF_XA    = ALIGN256(OFF_CSR   + (size_t)N_EDGES * 4);   // half[(N+1)*64]
static const size_t OFF_XB    = ALIGN256(OFF_XA + (size_t)(N_NODES + 1) * D_FEAT * 2);

__device__ __forceinline__ unsigned pack_h2(float a, float b) {
    union { __half2 h; unsigned u; } c;
    c.h = __floats2half2_rn(a, b);
    return c.u;
}
__device__ __forceinline__ float2 unpack_h2(unsigned u) {
    union { unsigned u; __half2 h; } c;
    c.u = u;
    return __half22float2(c.h);
}

// ---------------- preprocessing: zero-global-atomic counting sort ----------------

// ONE pass: per-chunk LDS histogram of src AND dst packed 4xu8 per word.
// (r7 kept this; it was bundled with the degree-sort regression. r7's sort
// kernels (contended global atomics on 16 cache lines + ascending straggler
// tail in hops) are REVERTED this round.)
__global__ __launch_bounds__(256, 1) void k_hist(const int* __restrict__ src,
                                                 const int* __restrict__ dst,
                                                 unsigned* __restrict__ p) {
    __shared__ unsigned h[NWORD];  // 100,000 B
    int t = threadIdx.x;
    int base = blockIdx.x * CHUNK;
    for (int w = t; w < NWORD; w += 256) h[w] = 0u;
    __syncthreads();
    for (int j = t; j < CHUNK; j += 256) {
        int s = src[base + j], d = dst[base + j];
        if (s != d) {
            atomicAdd(&h[s >> 1], 1u << (8 * (s & 1)));        // src: bytes 0/1
            atomicAdd(&h[d >> 1], 65536u << (8 * (d & 1)));    // dst: bytes 2/3
        }
    }
    __syncthreads();
    unsigned* o = p + (size_t)blockIdx.x * NWORD;
    for (int w = t; w < NWORD; w += 256) o[w] = h[w];
}

// One coalesced reduction of the packed partials -> dinv (from src bytes)
// AND totW (dst totals, u16-packed). Byte-lane sums stay < 256 (deg <= ~60).
__global__ void k_sum(const unsigned* __restrict__ p, float* __restrict__ dinv,
                      unsigned* __restrict__ totW) {
    int w = blockIdx.x * blockDim.x + threadIdx.x;
    if (w >= NWORD) return;
    unsigned s0 = 0, s1 = 0, s2 = 0, s3 = 0;
    #pragma unroll 4
    for (int c = 0; c < NPART; c += 4) {
        s0 += p[(size_t)(c + 0) * NWORD + w];
        s1 += p[(size_t)(c + 1) * NWORD + w];
        s2 += p[(size_t)(c + 2) * NWORD + w];
        s3 += p[(size_t)(c + 3) * NWORD + w];
    }
    unsigned s = (s0 + s1) + (s2 + s3);
    dinv[2 * w + 0] = rsqrtf((float)((s & 0xffu) + 1u));          // +1 self loop
    dinv[2 * w + 1] = rsqrtf((float)(((s >> 8) & 0xffu) + 1u));
    totW[w] = ((s >> 16) & 0xffu) | ((s >> 24) << 16);            // dst degs packed u16
}

// scan stage 1: per-block (1024 nodes) sums of totW (100KB total)
__global__ void k_scan_sums(const unsigned* __restrict__ totW, int* __restrict__ bsum) {
    __shared__ int lds[256];
    int b = blockIdx.x, t = threadIdx.x;
    int wend = min((b + 1) * SCAN_WORDS, NWORD);
    int tot = 0;
    for (int w = b * SCAN_WORDS + t; w < wend; w += 256) {
        unsigned v = totW[w];
        tot += (int)(v & 0xffffu) + (int)(v >> 16);
    }
    lds[t] = tot; __syncthreads();
    for (int str = 128; str > 0; str >>= 1) {
        if (t < str) lds[t] += lds[t + str];
        __syncthreads();
    }
    if (t == 0) bsum[b] = lds[0];
}

// scan stage 2: single-wave exclusive scan of the 49 block sums
__global__ void k_scan_top(int* __restrict__ bsum) {
    int lane = threadIdx.x;  // blockDim = 64
    int orig = (lane < SCAN_NB) ? bsum[lane] : 0;
    int v = orig;
    for (int d = 1; d < 64; d <<= 1) {
        int u = __shfl_up(v, d, 64);
        if (lane >= d) v += u;
    }
    if (lane < SCAN_NB) bsum[lane] = v - orig;  // exclusive
}

// scan stage 3: down-sweep writing off[] only
__global__ void k_scan_downA(const unsigned* __restrict__ totW, const int* __restrict__ bsum,
                             int* __restrict__ off) {
    __shared__ int lds[256];
    int b = blockIdx.x, t = threadIdx.x;
    int w0 = b * SCAN_WORDS + 2 * t;
    unsigned t0 = (w0 < NWORD) ? totW[w0] : 0u;
    unsigned t1 = (w0 + 1 < NWORD) ? totW[w0 + 1] : 0u;
    int n[4] = { (int)(t0 & 0xffffu), (int)(t0 >> 16),
                 (int)(t1 & 0xffffu), (int)(t1 >> 16) };
    int tsum = (n[0] + n[1]) + (n[2] + n[3]);
    lds[t] = tsum; __syncthreads();
    int x = tsum;
    for (int d = 1; d < 256; d <<= 1) {   // Hillis-Steele inclusive scan
        int u = (t >= d) ? lds[t - d] : 0;
        __syncthreads();
        x += u;
        lds[t] = x;
        __syncthreads();
    }
    int pfx = (x - tsum) + bsum[b];
    #pragma unroll
    for (int j = 0; j < 4; ++j) {
        int node = 2 * w0 + j;
        if (node < N_NODES) {
            off[node] = pfx;
            pfx += n[j];
        } else if (node == N_NODES) {
            off[node] = pfx;
        }
    }
}

// bases[c][node] = off[node] + prefix over chunks of per-chunk dst count.
// One LANE per node: reads and writes lane-consecutive -> fully coalesced.
__global__ void k_bases(const unsigned* __restrict__ p, const int* __restrict__ off,
                        int* __restrict__ bases) {
    int node = blockIdx.x * blockDim.x + threadIdx.x;
    if (node >= N_NODES) return;
    int w = node >> 1;
    int sh = 16 + 8 * (node & 1);  // dst byte lane
    int acc = off[node];
    for (int c = 0; c < NPART; ++c) {
        bases[(size_t)c * N_NODES + node] = acc;
        acc += (int)((p[(size_t)c * NWORD + w] >> sh) & 0xffu);
    }
}

// scatter via LDS re-histogram (dst only, u16-packed): the LDS atomicAdd
// return value IS the within-(chunk,dst) slot. No global atomics.
__global__ __launch_bounds__(256, 1) void k_scatter(const int* __restrict__ src,
                                                    const int* __restrict__ dst,
                                                    const int* __restrict__ bases,
                                                    int* __restrict__ csr) {
    __shared__ unsigned h[NWORD];  // 100,000 B
    int t = threadIdx.x;
    int base = blockIdx.x * CHUNK;
    const int* bp = bases + (size_t)blockIdx.x * N_NODES;
    for (int w = t; w < NWORD; w += 256) h[w] = 0u;
    __syncthreads();
    for (int j = t; j < CHUNK; j += 256) {
        int s = src[base + j], d = dst[base + j];
        if (s == d) continue;
        unsigned old = atomicAdd(&h[d >> 1], (d & 1) ? 65536u : 1u);
        unsigned pw = (d & 1) ? (old >> 16) : (old & 0xffffu);
        csr[bp[d] + (int)pw] = s;
    }
}

// ---------------- compute kernels ----------------

// x0: feature -> out col 0 (fp32) and XB = y0 = dinv * x (fp16 compact).
// Also zeroes row N of XB (the predication zero-row for hop gathers).
__global__ void k_x0(const float4* __restrict__ feat4, float4* __restrict__ out4,
                     uint2* __restrict__ y0, const float* __restrict__ dinv) {
    int t = blockIdx.x * blockDim.x + threadIdx.x;  // over (N+1)*16
    if (t >= (N_NODES + 1) * 16) return;
    int row = t >> 4;
    if (row < N_NODES) {
        float4 v = feat4[t];
        out4[(size_t)row * (OUT_STRIDE / 4) + (t & 15)] = v;
        float di = dinv[row];
        uint2 w;
        w.x = pack_h2(v.x * di, v.y * di);
        w.y = pack_h2(v.z * di, v.w * di);
        y0[t] = w;
    } else {
        y0[t] = make_uint2(0u, 0u);  // zero row
    }
}

// Quad-node hop: 4 CONSECUTIVE nodes per wave (16 lanes x 8B each -> one
// gather instruction fetches 4 rows of 128B). Weight-free accumulate:
//   t_i = sum_{j->i} y[j] + y[i];  out = dinv*t;  y' = dinv^2*t.
// 4-deep gather + 4-wide csr prefetch. (r7's perm-sorted variant REVERTED:
// ascending degree order serialized heavy blocks at each hop's tail.)
template <bool WRITE_HALF>
__global__ __launch_bounds__(256) void k_hop4(
    const uint2* __restrict__ yin,   // (N+1) x 16 x uint2
    float4* __restrict__ outcol4,    // (float4*)out + k*16; row stride 144
    uint2* __restrict__ yout,
    const int* __restrict__ off, const int* __restrict__ csr,
    const float* __restrict__ dinv) {
    int qw = (blockIdx.x * blockDim.x + threadIdx.x) >> 6;  // quad id, < 12500
    int lane = threadIdx.x & 63;
    int f = lane & 15;                 // feature quad: features [4f, 4f+4)
    int node = qw * 4 + (lane >> 4);   // < 50000 exactly
    int e0 = off[node], e1 = off[node + 1];
    float di = dinv[node];
    uint2 sv = yin[node * 16 + f];
    float2 lo = unpack_h2(sv.x), hi = unpack_h2(sv.y);
    float a0 = lo.x, a1 = lo.y, a2 = hi.x, a3 = hi.y;  // self term

    int nm = e1 - e0;  // wave-wide max degree
    #pragma unroll
    for (int d = 32; d; d >>= 1) nm = max(nm, __shfl_xor(nm, d, 64));

    auto FETCH = [&](int j) -> int {
        int idx = e0 + j;
        int c = csr[idx < e1 ? idx : 0];  // safe broadcast addr
        return (idx < e1) ? c : N_NODES;  // zero row when exhausted
    };

    int c0 = FETCH(0), c1 = FETCH(1), c2 = FETCH(2), c3 = FETCH(3);
    for (int j = 0; j < nm; j += 4) {
        int d0 = FETCH(j + 4), d1 = FETCH(j + 5), d2 = FETCH(j + 6), d3 = FETCH(j + 7);
        uint2 q0 = yin[c0 * 16 + f];
        uint2 q1 = yin[c1 * 16 + f];
        uint2 q2 = yin[c2 * 16 + f];
        uint2 q3 = yin[c3 * 16 + f];
        float2 t;
        t = unpack_h2(q0.x); a0 += t.x; a1 += t.y;
        t = unpack_h2(q0.y); a2 += t.x; a3 += t.y;
        t = unpack_h2(q1.x); a0 += t.x; a1 += t.y;
        t = unpack_h2(q1.y); a2 += t.x; a3 += t.y;
        t = unpack_h2(q2.x); a0 += t.x; a1 += t.y;
        t = unpack_h2(q2.y); a2 += t.x; a3 += t.y;
        t = unpack_h2(q3.x); a0 += t.x; a1 += t.y;
        t = unpack_h2(q3.y); a2 += t.x; a3 += t.y;
        c0 = d0; c1 = d1; c2 = d2; c3 = d3;
    }

    outcol4[(size_t)node * (OUT_STRIDE / 4) + f] =
        make_float4(di * a0, di * a1, di * a2, di * a3);
    if (WRITE_HALF) {
        float di2 = di * di;
        uint2 w;
        w.x = pack_h2(di2 * a0, di2 * a1);
        w.y = pack_h2(di2 * a2, di2 * a3);
        yout[node * 16 + f] = w;
        if (blockIdx.x == 0 && threadIdx.x < 16)
            yout[N_NODES * 16 + threadIdx.x] = make_uint2(0u, 0u);  // zero row
    }
}

// ---------------- launch ----------------

extern "C" void kernel_launch(void* const* d_in, const int* in_sizes, int n_in,
                              void* d_out, int out_size, void* d_ws, size_t ws_size,
                              hipStream_t stream) {
    const float* feature = (const float*)d_in[0];
    const int* edge = (const int*)d_in[1];
    const int* src = edge;            // edge_index[0]
    const int* dst = edge + N_EDGES;  // edge_index[1]
    float* out = (float*)d_out;
    char* ws = (char*)d_ws;

    unsigned* p     = (unsigned*)(ws + OFF_P);
    int*      bases = (int*)(ws + OFF_BASES);
    int*      off   = (int*)(ws + OFF_OFF);
    int*      bsum  = (int*)(ws + OFF_BSUM);
    unsigned* totW  = (unsigned*)(ws + OFF_TOTW);
    float*    dinv  = (float*)(ws + OFF_DINV);
    int*      csr   = (int*)(ws + OFF_CSR);
    uint2*    xa    = (uint2*)(ws + OFF_XA);
    uint2*    xb    = (uint2*)(ws + OFF_XB);

    const int TB = 256;
    const int NB_NODES = (N_NODES + TB - 1) / TB;
    // ---- build normalization + CSR: zero global atomics, zero memsets
    k_hist<<<NPART, 256, 0, stream>>>(src, dst, p);
    k_sum<<<(NWORD + TB - 1) / TB, TB, 0, stream>>>(p, dinv, totW);
    k_x0<<<((N_NODES + 1) * 16 + TB - 1) / TB, TB, 0, stream>>>(
        (const float4*)feature, (float4*)out, xb, dinv);
    k_scan_sums<<<SCAN_NB, 256, 0, stream>>>(totW, bsum);
    k_scan_top<<<1, 64, 0, stream>>>(bsum);
    k_scan_downA<<<SCAN_NB, 256, 0, stream>>>(totW, bsum, off);
    k_bases<<<NB_NODES, TB, 0, stream>>>(p, off, bases);
    k_scatter<<<NPART, 256, 0, stream>>>(src, dst, bases, csr);
    // ---- K hops, fp16 ping-pong y buffers (XB -> XA -> XB -> ...)
    const int hop_blocks = (N_NODES / 4) * 64 / TB;  // 3125
    for (int k = 1; k <= K_HOPS; ++k) {
        const uint2* yin = (k & 1) ? xb : xa;
        uint2* yout      = (k & 1) ? xa : xb;
        float4* outcol4 = (float4*)out + (size_t)k * 16;
        if (k < K_HOPS)
            k_hop4<true><<<hop_blocks, TB, 0, stream>>>(yin, outcol4, yout, off, csr, dinv);
        else
            k_hop4<false><<<hop_blocks, TB, 0, stream>>>(yin, outcol4, nullptr, off, csr, dinv);
    }
}